// Round 13
// baseline (18.978 us; speedup 1.0000x reference)
//
#include <hip/hip_runtime.h>
#include <math.h>

#define BB 64
#define LL 512
#define DD 768
#define HH 768
#define KK 128
#define FLAG_MAGIC 0x0BADF00D

static __device__ __forceinline__ float4 fmax4(float4 a, float4 b) {
    float4 r;
    r.x = fmaxf(a.x, b.x); r.y = fmaxf(a.y, b.y);
    r.z = fmaxf(a.z, b.z); r.w = fmaxf(a.w, b.w);
    return r;
}

// ---------------------------------------------------------------------------
// Single kernel: {scan + gather + GEMM1} then per-block k-slice GEMM2 partial
// + flag publish; jt==0 blocks spin-reduce the 12 partials -> out.
// grid: (12 j-tiles of 64, 16 b-tiles of 4) = 192 blocks ; block: 1024 (16 wv)
// 192 blocks x 1 block/CU <= 256 CUs -> all co-resident, spin is safe.
// ws: partial[16][12][4][128] floats (393 KB) | flags[16*12] ints.
// Flags: producer stores FLAG_MAGIC (agent release), consumer resets to 0 -
// works with 0xAA-poisoned ws on first call, replay-clean afterwards.
// ---------------------------------------------------------------------------
__global__ __launch_bounds__(1024, 1) void halton_one_kernel(
    const float* __restrict__ enc,        // (B, L, D)
    const float* __restrict__ W1,         // (D, H)
    const float* __restrict__ b1,         // (H)
    const float* __restrict__ W2,         // (H, K)
    const float* __restrict__ b2,         // (K)
    const int*   __restrict__ valid_mask, // (B, L)
    const int*   __restrict__ pos_span,   // (B, 2)
    float*       __restrict__ out,        // (B, K)
    float*       __restrict__ ws_partial, // [16][12][4][128]
    int*         __restrict__ ws_flags)   // [16][12]
{
    __shared__ int    s_idx[4][40];
    __shared__ int    s_count[4];
    __shared__ float4 s_red[4][4][192];    // [g][bl][fc] 49 KB
    __shared__ float  s_feat[4][DD];       // 12 KB
    __shared__ float  s_part[16][4][64];   // [kslice][batch][col] 16 KB
    __shared__ float  s_hh[4][64];         // relu(h) slice, 1 KB
    __shared__ float  s_ep[8][128];        // epilogue partials, 4 KB

    const int tid   = threadIdx.x;
    const int jt    = blockIdx.x;          // 0..11
    const int bt    = blockIdx.y;          // 0..15
    const int jbase = jt * 64;
    const int bbase = bt * 4;
    const int lane  = tid & 63;
    const int w     = tid >> 6;            // wave 0..15
    const int j     = jbase + lane;

    // ---- entry prefetches (independent of scan/gather) ---------------------
    const float rb1 = b1[jbase + lane];            // used in combine
    float rb2 = 0.f;                               // consumer bias prefetch
    if (jt == 0 && tid < 512) rb2 = b2[tid & 127];
    const int   kp  = w * 48;                      // this wave's first k
    float w0p = W1[(kp + 0) * HH + j];             // first GEMM iter's W1
    float w1p = W1[(kp + 1) * HH + j];
    float w2p = W1[(kp + 2) * HH + j];
    float w3p = W1[(kp + 3) * HH + j];
    const int bl_g = w & 3;                        // gather batch
    const int g_g  = w >> 2;                       // gather row-group
    const int bgat = bbase + bl_g;
    const int lo   = pos_span[bgat * 2 + 0];
    const int hi   = pos_span[bgat * 2 + 1];       // <= 39 by construction

    // ---- Phase 0: prefetched ballot scan, waves 0..3 -----------------------
    if (w < 4) {
        const int b = bbase + w;
        int v[8];
        #pragma unroll
        for (int c = 0; c < 8; ++c)        // 8 independent loads, one latency
            v[c] = valid_mask[b * LL + c * 64 + lane];
        int count = 0;
        #pragma unroll
        for (int c = 0; c < 8; ++c) {
            unsigned long long mk = __ballot(v[c] == 1);
            if (v[c] == 1) {
                int rank = count + __popcll(mk & ((1ull << lane) - 1ull));
                if (rank < 40) s_idx[w][rank] = c * 64 + lane;
            }
            count += __popcll(mk);
        }
        if (lane == 0) s_count[w] = count;
    }
    __syncthreads();

    // ---- Phase 1: span-max gather, wave = (batch, row-group) ---------------
    {
        const int count = s_count[bl_g];
        const int pend  = min(hi, count - 1);

        const float4 ninf = make_float4(-INFINITY, -INFINITY, -INFINITY, -INFINITY);
        float4 m0 = ninf, m1 = ninf, m2 = ninf;   // row p
        float4 n0 = ninf, n1 = ninf, n2 = ninf;   // row p+4
        for (int p = lo + g_g; p <= pend; p += 8) {
            const float4* r4 = (const float4*)&enc[((long)bgat * LL + s_idx[bl_g][p]) * DD];
            m0 = fmax4(m0, r4[lane]);
            m1 = fmax4(m1, r4[lane + 64]);
            m2 = fmax4(m2, r4[lane + 128]);
            if (p + 4 <= pend) {
                const float4* q4 = (const float4*)&enc[((long)bgat * LL + s_idx[bl_g][p + 4]) * DD];
                n0 = fmax4(n0, q4[lane]);
                n1 = fmax4(n1, q4[lane + 64]);
                n2 = fmax4(n2, q4[lane + 128]);
            }
        }
        m0 = fmax4(m0, n0); m1 = fmax4(m1, n1); m2 = fmax4(m2, n2);
        if (hi >= count) {                 // zero row(s) inside span
            const float4 z = make_float4(0.f, 0.f, 0.f, 0.f);
            m0 = fmax4(m0, z); m1 = fmax4(m1, z); m2 = fmax4(m2, z);
        }
        s_red[g_g][bl_g][lane]       = m0;
        s_red[g_g][bl_g][lane + 64]  = m1;
        s_red[g_g][bl_g][lane + 128] = m2;
    }
    __syncthreads();

    // ---- Phase 1.5 (no barrier): per-wave tree over ONLY this wave's slice -
    if (lane < 48) {
        const int bl = lane / 12;
        const int kf = w * 12 + lane % 12;
        float4 r = fmax4(fmax4(s_red[0][bl][kf], s_red[1][bl][kf]),
                         fmax4(s_red[2][bl][kf], s_red[3][bl][kf]));
        ((float4*)&s_feat[bl][0])[kf] = r;
    }
    // wave-local LDS write->read: ordered by lgkmcnt, no block barrier needed

    // ---- Phase 2: GEMM1, wave = k-slice of 48, thread = 1 col x 4 batches --
    {
        const float4* f40 = (const float4*)&s_feat[0][0];
        const float4* f41 = (const float4*)&s_feat[1][0];
        const float4* f42 = (const float4*)&s_feat[2][0];
        const float4* f43 = (const float4*)&s_feat[3][0];

        float a0, a1, a2, a3;
        {   // k4 = 0: use entry-prefetched W1 values
            const int kf = w * 12;
            const float4 fv0 = f40[kf], fv1 = f41[kf], fv2 = f42[kf], fv3 = f43[kf];
            a0 = fv0.x * w0p + fv0.y * w1p + fv0.z * w2p + fv0.w * w3p;
            a1 = fv1.x * w0p + fv1.y * w1p + fv1.z * w2p + fv1.w * w3p;
            a2 = fv2.x * w0p + fv2.y * w1p + fv2.z * w2p + fv2.w * w3p;
            a3 = fv3.x * w0p + fv3.y * w1p + fv3.z * w2p + fv3.w * w3p;
        }
        #pragma unroll 4
        for (int k4 = 1; k4 < 12; ++k4) {
            const int kf = w * 12 + k4;
            const int k  = kf * 4;
            const float4 fv0 = f40[kf];    // LDS b128 broadcasts
            const float4 fv1 = f41[kf];
            const float4 fv2 = f42[kf];
            const float4 fv3 = f43[kf];
            const float w0 = W1[(k + 0) * HH + j];   // coalesced, once/block
            const float w1 = W1[(k + 1) * HH + j];
            const float w2 = W1[(k + 2) * HH + j];
            const float w3 = W1[(k + 3) * HH + j];
            a0 += fv0.x * w0 + fv0.y * w1 + fv0.z * w2 + fv0.w * w3;
            a1 += fv1.x * w0 + fv1.y * w1 + fv1.z * w2 + fv1.w * w3;
            a2 += fv2.x * w0 + fv2.y * w1 + fv2.z * w2 + fv2.w * w3;
            a3 += fv3.x * w0 + fv3.y * w1 + fv3.z * w2 + fv3.w * w3;
        }
        s_part[w][0][lane] = a0;
        s_part[w][1][lane] = a1;
        s_part[w][2][lane] = a2;
        s_part[w][3][lane] = a3;
    }
    __syncthreads();

    // ---- combine: threads 0..255 -> relu(h) slice kept in LDS --------------
    if (tid < 256) {
        const int bl  = tid >> 6;
        const int col = tid & 63;
        float r = rb1;                     // b1[jbase+col], prefetched
        #pragma unroll
        for (int q = 0; q < 16; ++q) r += s_part[q][bl][col];
        s_hh[bl][col] = fmaxf(r, 0.f);
    }
    __syncthreads();

    // ---- epilogue: GEMM2 k-slice partial = s_hh @ W2[jbase..jbase+64, :] ---
    {
        const int col2 = tid & 127;        // output col 0..127
        const int bl   = (tid >> 7) & 3;   // batch
        const int kh   = tid >> 9;         // k-half 0..1 (32 k each)
        float a0 = 0.f, a1 = 0.f, a2 = 0.f, a3 = 0.f;
        #pragma unroll 8
        for (int i = 0; i < 32; i += 4) {
            const int k0 = kh * 32 + i;    // local k within the 64-slice
            a0 += s_hh[bl][k0 + 0] * W2[(jbase + k0 + 0) * KK + col2];
            a1 += s_hh[bl][k0 + 1] * W2[(jbase + k0 + 1) * KK + col2];
            a2 += s_hh[bl][k0 + 2] * W2[(jbase + k0 + 2) * KK + col2];
            a3 += s_hh[bl][k0 + 3] * W2[(jbase + k0 + 3) * KK + col2];
        }
        s_ep[(bl << 1) | kh][col2] = (a0 + a1) + (a2 + a3);
    }
    __syncthreads();

    // publish partial (agent-scope -> device-coherent), then release flag
    if (tid < 512) {
        const int bl  = tid >> 7;
        const int col = tid & 127;
        const float p = s_ep[bl * 2][col] + s_ep[bl * 2 + 1][col];
        __hip_atomic_store(&ws_partial[((bt * 12 + jt) * 4 + bl) * 128 + col], p,
                           __ATOMIC_RELAXED, __HIP_MEMORY_SCOPE_AGENT);
    }
    __syncthreads();                       // drains all partial stores
    if (tid == 0)
        __hip_atomic_store(&ws_flags[bt * 12 + jt], (int)FLAG_MAGIC,
                           __ATOMIC_RELEASE, __HIP_MEMORY_SCOPE_AGENT);

    // ---- consumer: jt==0 blocks reduce the 12 partials -> out --------------
    if (jt == 0) {
        if (w == 0) {                      // wave 0 spins on the 12 flags
            bool done;
            do {
                int f = (lane < 12)
                    ? __hip_atomic_load(&ws_flags[bt * 12 + lane],
                                        __ATOMIC_ACQUIRE, __HIP_MEMORY_SCOPE_AGENT)
                    : (int)FLAG_MAGIC;
                done = __all(f == (int)FLAG_MAGIC);
            } while (!done);
        }
        __syncthreads();

        if (tid < 512) {
            const int bl  = tid >> 7;
            const int col = tid & 127;
            float r = rb2;                 // b2[col], prefetched at entry
            #pragma unroll
            for (int q = 0; q < 12; ++q)
                r += __hip_atomic_load(&ws_partial[((bt * 12 + q) * 4 + bl) * 128 + col],
                                       __ATOMIC_RELAXED, __HIP_MEMORY_SCOPE_AGENT);
            out[(bbase + bl) * KK + col] = r;
        }
        if (tid < 12)                      // reset flags for the next replay
            __hip_atomic_store(&ws_flags[bt * 12 + tid], 0,
                               __ATOMIC_RELAXED, __HIP_MEMORY_SCOPE_AGENT);
    }
}

extern "C" void kernel_launch(void* const* d_in, const int* in_sizes, int n_in,
                              void* d_out, int out_size, void* d_ws, size_t ws_size,
                              hipStream_t stream) {
    const float* enc        = (const float*)d_in[0];
    const float* W1         = (const float*)d_in[1];
    const float* b1         = (const float*)d_in[2];
    const float* W2         = (const float*)d_in[3];
    const float* b2         = (const float*)d_in[4];
    const int*   valid_mask = (const int*)d_in[5];
    const int*   pos_span   = (const int*)d_in[6];
    // d_in[7] = mask_span: dead code (mask_feat unused by the reference output)
    float* out        = (float*)d_out;
    float* ws_partial = (float*)d_ws;                 // 16*12*4*128 floats
    int*   ws_flags   = (int*)d_ws + 16 * 12 * 4 * 128;

    halton_one_kernel<<<dim3(12, 16), 1024, 0, stream>>>(
        enc, W1, b1, W2, b2, valid_mask, pos_span, out, ws_partial, ws_flags);
}